// Round 2
// baseline (412.245 us; speedup 1.0000x reference)
//
#include <hip/hip_runtime.h>

#define NG 8000
#define V1 2562
#define V2 10242
#define V3 40962
#define E1 7680
#define E2 30720
#define E3 122880
#define NPRED (V1 + V2 + V3)   /* 53766 */
#define NPK   (NG + NPRED)     /* 61766 */
#define ND1   (3 * NG)         /* 24000 */

__device__ __forceinline__ double block_reduce_add(double v, double* sm) {
    int lane = threadIdx.x & 63;
    int wid  = threadIdx.x >> 6;
    for (int off = 32; off > 0; off >>= 1) v += __shfl_down(v, off, 64);
    if (lane == 0) sm[wid] = v;
    __syncthreads();
    double r = 0.0;
    if (wid == 0) {
        int nw = blockDim.x >> 6;
        r = (lane < nw) ? sm[lane] : 0.0;
        for (int off = 32; off > 0; off >>= 1) r += __shfl_down(r, off, 64);
    }
    return r;  /* valid on thread 0 */
}

__global__ void k_init(unsigned int* __restrict__ mins, double* __restrict__ acc) {
    int i = blockIdx.x * blockDim.x + threadIdx.x;
    if (i < 8) acc[i] = 0.0;
    int stride = gridDim.x * blockDim.x;
    for (int k = i; k < ND1 + NPRED; k += stride) mins[k] = 0x7f800000u; /* +inf */
}

__global__ void k_pack(const float* __restrict__ gt,
                       const float* __restrict__ p1, const float* __restrict__ p2,
                       const float* __restrict__ p3, float4* __restrict__ pk) {
    int stride = gridDim.x * blockDim.x;
    for (int i = blockIdx.x * blockDim.x + threadIdx.x; i < NPK; i += stride) {
        const float* src; int k;
        if (i < NG) { src = gt; k = i; }
        else {
            int t = i - NG;
            if (t < V1)            { src = p1; k = t; }
            else if (t < V1 + V2)  { src = p2; k = t - V1; }
            else                   { src = p3; k = t - V1 - V2; }
        }
        float x = src[3 * k], y = src[3 * k + 1], z = src[3 * k + 2];
        pk[i] = make_float4(x, y, z, x * x + y * y + z * z);
    }
}

/* thread t = A point; loop over B[j0,j1) at wave-uniform addresses.
   d = An + Bn - 2*A.B ; min tracked raw, clamped >=0 once at the end
   (max(.,0) is monotone so it commutes with min). */
__launch_bounds__(256)
__global__ void k_pair(const float4* __restrict__ Ap, int NA,
                       const float4* __restrict__ Bp, int NB,
                       int chunk, unsigned int* __restrict__ outMin) {
    int t  = blockIdx.x * blockDim.x + threadIdx.x;
    int j0 = blockIdx.y * chunk;
    int j1 = min(NB, j0 + chunk);
    if (t >= NA) return;
    float4 a = Ap[t];
    float an = a.w;
    float ax = -2.0f * a.x, ay = -2.0f * a.y, az = -2.0f * a.z;
    float inf = __builtin_inff();
    float m0 = inf, m1 = inf, m2 = inf, m3 = inf, m4 = inf, m5 = inf, m6 = inf, m7 = inf;
    int j = j0;
#define STEP(mm, bb) { float d = an + bb.w; d = fmaf(ax, bb.x, d); \
                       d = fmaf(ay, bb.y, d); d = fmaf(az, bb.z, d); \
                       mm = fminf(mm, d); }
    for (; j + 8 <= j1; j += 8) {
        float4 b0 = Bp[j + 0]; float4 b1 = Bp[j + 1];
        float4 b2 = Bp[j + 2]; float4 b3 = Bp[j + 3];
        float4 b4 = Bp[j + 4]; float4 b5 = Bp[j + 5];
        float4 b6 = Bp[j + 6]; float4 b7 = Bp[j + 7];
        STEP(m0, b0) STEP(m1, b1) STEP(m2, b2) STEP(m3, b3)
        STEP(m4, b4) STEP(m5, b5) STEP(m6, b6) STEP(m7, b7)
    }
    for (; j < j1; ++j) { float4 b = Bp[j]; STEP(m0, b) }
#undef STEP
    m0 = fminf(m0, m1); m2 = fminf(m2, m3); m4 = fminf(m4, m5); m6 = fminf(m6, m7);
    m0 = fminf(m0, m2); m4 = fminf(m4, m6);
    float m = fmaxf(fminf(m0, m4), 0.0f);
    atomicMin(outMin + t, __float_as_uint(m));
}

__global__ void k_reduce_chamfer(const unsigned int* __restrict__ d1,
                                 const unsigned int* __restrict__ d2,
                                 double* __restrict__ acc) {
    __shared__ double sm[8];
    double s = 0.0;
    int total  = ND1 + NPRED;
    int stride = gridDim.x * blockDim.x;
    for (int i = blockIdx.x * blockDim.x + threadIdx.x; i < total; i += stride) {
        double v, w;
        if (i < ND1) { v = (double)__uint_as_float(d1[i]); w = 1.0 / NG; }
        else {
            int t = i - ND1;
            v = (double)__uint_as_float(d2[t]);
            w = (t < V1) ? (1.0 / V1) : ((t < V1 + V2) ? (1.0 / V2) : (1.0 / V3));
        }
        s += v * w;
    }
    s = block_reduce_add(s, sm);
    if (threadIdx.x == 0) atomicAdd(acc + 0, s);
}

__global__ void k_edge(const float* __restrict__ p1, const float* __restrict__ p2,
                       const float* __restrict__ p3,
                       const int* __restrict__ e1, const int* __restrict__ e2,
                       const int* __restrict__ e3, double* __restrict__ acc) {
    __shared__ double sm[8];
    double s = 0.0;
    int total  = E1 + E2 + E3;
    int stride = gridDim.x * blockDim.x;
    for (int i = blockIdx.x * blockDim.x + threadIdx.x; i < total; i += stride) {
        const float* p; const int* e; int k; double w;
        if (i < E1)            { p = p1; e = e1; k = i;            w = 1.0 / E1; }
        else if (i < E1 + E2)  { p = p2; e = e2; k = i - E1;       w = 1.0 / E2; }
        else                   { p = p3; e = e3; k = i - E1 - E2;  w = 1.0 / E3; }
        int u = e[2 * k], v = e[2 * k + 1];
        float dx = p[3 * u]     - p[3 * v];
        float dy = p[3 * u + 1] - p[3 * v + 1];
        float dz = p[3 * u + 2] - p[3 * v + 2];
        s += w * (double)(dx * dx + dy * dy + dz * dz);
    }
    s = block_reduce_add(s, sm);
    if (threadIdx.x == 0) atomicAdd(acc + 1, s);
}

__global__ void k_lap(const float* __restrict__ f1, const float* __restrict__ f2,
                      const float* __restrict__ f3,
                      const float* __restrict__ p1, const float* __restrict__ p2,
                      const float* __restrict__ p3,
                      const int* __restrict__ l1, const int* __restrict__ l2,
                      const int* __restrict__ l3, double* __restrict__ acc) {
    __shared__ double sm[8];
    double s = 0.0;
    int stride = gridDim.x * blockDim.x;
    for (int i = blockIdx.x * blockDim.x + threadIdx.x; i < NPRED; i += stride) {
        const float* f; const float* p; const int* l; int k; double w;
        if (i < V1)            { f = f1; p = p1; l = l1; k = i;            w = 0.2 / V1; }
        else if (i < V1 + V2)  { f = f2; p = p2; l = l2; k = i - V1;       w = 1.0 / V2; }
        else                   { f = f3; p = p3; l = l3; k = i - V1 - V2;  w = 1.0 / V3; }
        const int* row = l + 10 * k;
        float sfx = 0.f, sfy = 0.f, sfz = 0.f, spx = 0.f, spy = 0.f, spz = 0.f;
#pragma unroll
        for (int q = 0; q < 8; ++q) {
            int n = row[q];
            if (n >= 0) {
                sfx += f[3 * n]; sfy += f[3 * n + 1]; sfz += f[3 * n + 2];
                spx += p[3 * n]; spy += p[3 * n + 1]; spz += p[3 * n + 2];
            }
        }
        float inv = 1.0f / (float)row[9];
        float dx = (f[3 * k]     - p[3 * k])     - (sfx - spx) * inv;
        float dy = (f[3 * k + 1] - p[3 * k + 1]) - (sfy - spy) * inv;
        float dz = (f[3 * k + 2] - p[3 * k + 2]) - (sfz - spz) * inv;
        s += w * (double)(dx * dx + dy * dy + dz * dz);
    }
    s = block_reduce_add(s, sm);
    if (threadIdx.x == 0) atomicAdd(acc + 2, s);
}

__global__ void k_final(const double* __restrict__ acc, float* __restrict__ out) {
    if (threadIdx.x == 0 && blockIdx.x == 0) {
        double ch = acc[0], ed = acc[1], lp = acc[2];
        out[0] = (float)(100.0 * ch + 0.1 * ed + 0.3 * lp);
        out[1] = (float)ch;
        out[2] = (float)ed;
        out[3] = (float)lp;
    }
}

extern "C" void kernel_launch(void* const* d_in, const int* in_sizes, int n_in,
                              void* d_out, int out_size, void* d_ws, size_t ws_size,
                              hipStream_t stream) {
    const float *pp[3], *pf[3], *gt;
    const int *ed[3], *li[3];
    if (in_sizes[1] == 3 * V1) {
        /* setup_inputs() dict order: (pts,feats,edges,lap)*3, gt */
        pp[0] = (const float*)d_in[0];  pf[0] = (const float*)d_in[1];
        ed[0] = (const int*)d_in[2];    li[0] = (const int*)d_in[3];
        pp[1] = (const float*)d_in[4];  pf[1] = (const float*)d_in[5];
        ed[1] = (const int*)d_in[6];    li[1] = (const int*)d_in[7];
        pp[2] = (const float*)d_in[8];  pf[2] = (const float*)d_in[9];
        ed[2] = (const int*)d_in[10];   li[2] = (const int*)d_in[11];
        gt = (const float*)d_in[12];
    } else {
        /* reference signature order */
        pp[0] = (const float*)d_in[0];  pp[1] = (const float*)d_in[1];  pp[2] = (const float*)d_in[2];
        pf[0] = (const float*)d_in[3];  pf[1] = (const float*)d_in[4];  pf[2] = (const float*)d_in[5];
        gt    = (const float*)d_in[6];
        ed[0] = (const int*)d_in[7];    ed[1] = (const int*)d_in[8];    ed[2] = (const int*)d_in[9];
        li[0] = (const int*)d_in[10];   li[1] = (const int*)d_in[11];   li[2] = (const int*)d_in[12];
    }

    char* ws = (char*)d_ws;
    double*       acc = (double*)ws;                       /* 8 doubles (64 B)   */
    float4*       pk  = (float4*)(ws + 64);                /* NPK float4         */
    unsigned int* d1  = (unsigned int*)(ws + 64 + (size_t)NPK * 16); /* 3*NG     */
    unsigned int* d2  = d1 + ND1;                          /* NPRED              */

    k_init<<<160, 256, 0, stream>>>(d1, acc);
    k_pack<<<242, 256, 0, stream>>>(gt, pp[0], pp[1], pp[2], pk);

    const float4* gtp = pk;
    const float4* pkp[3] = { pk + NG, pk + NG + V1, pk + NG + V1 + V2 };
    const int Vn[3]  = { V1, V2, V3 };
    const int chA[3] = { 8, 8, 16 };   /* chunks of pred for the gt-side pass  */
    const int chB[3] = { 16, 8, 6 };   /* chunks of gt for the pred-side pass  */

    /* d1[i][t] = min over pred_i of dist(gt_t, .) */
    for (int i = 0; i < 3; ++i) {
        int chunk = (Vn[i] + chA[i] - 1) / chA[i];
        dim3 g((NG + 255) / 256, chA[i]);
        k_pair<<<g, 256, 0, stream>>>(gtp, NG, pkp[i], Vn[i], chunk, d1 + i * NG);
    }
    /* d2[j] = min over gt of dist(pred_j, .) */
    unsigned int* d2off[3] = { d2, d2 + V1, d2 + V1 + V2 };
    for (int i = 0; i < 3; ++i) {
        int chunk = (NG + chB[i] - 1) / chB[i];
        dim3 g((Vn[i] + 255) / 256, chB[i]);
        k_pair<<<g, 256, 0, stream>>>(pkp[i], Vn[i], gtp, NG, chunk, d2off[i]);
    }

    k_reduce_chamfer<<<152, 256, 0, stream>>>(d1, d2, acc);
    k_edge<<<256, 256, 0, stream>>>(pp[0], pp[1], pp[2], ed[0], ed[1], ed[2], acc);
    k_lap<<<128, 256, 0, stream>>>(pf[0], pf[1], pf[2], pp[0], pp[1], pp[2],
                                   li[0], li[1], li[2], acc);
    k_final<<<1, 64, 0, stream>>>(acc, (float*)d_out);
}

// Round 3
// 243.044 us; speedup vs baseline: 1.6962x; 1.6962x over previous
//
#include <hip/hip_runtime.h>

#define NG 8000
#define V1 2562
#define V2 10242
#define V3 40962
#define E1 7680
#define E2 30720
#define E3 122880
#define NPRED (V1 + V2 + V3)   /* 53766 */
#define NPK   (NG + NPRED)     /* 61766 */
#define ND1   (3 * NG)         /* 24000 */

__device__ __forceinline__ double block_reduce_add(double v, double* sm) {
    int lane = threadIdx.x & 63;
    int wid  = threadIdx.x >> 6;
    for (int off = 32; off > 0; off >>= 1) v += __shfl_down(v, off, 64);
    if (lane == 0) sm[wid] = v;
    __syncthreads();
    double r = 0.0;
    if (wid == 0) {
        int nw = blockDim.x >> 6;
        r = (lane < nw) ? sm[lane] : 0.0;
        for (int off = 32; off > 0; off >>= 1) r += __shfl_down(r, off, 64);
    }
    return r;  /* valid on thread 0 */
}

__global__ void k_init(unsigned int* __restrict__ mins, double* __restrict__ acc) {
    int i = blockIdx.x * blockDim.x + threadIdx.x;
    if (i < 8) acc[i] = 0.0;
    int stride = gridDim.x * blockDim.x;
    for (int k = i; k < ND1 + NPRED; k += stride) mins[k] = 0x7f800000u; /* +inf */
}

__global__ void k_pack(const float* __restrict__ gt,
                       const float* __restrict__ p1, const float* __restrict__ p2,
                       const float* __restrict__ p3, float4* __restrict__ pk) {
    int stride = gridDim.x * blockDim.x;
    for (int i = blockIdx.x * blockDim.x + threadIdx.x; i < NPK; i += stride) {
        const float* src; int k;
        if (i < NG) { src = gt; k = i; }
        else {
            int t = i - NG;
            if (t < V1)            { src = p1; k = t; }
            else if (t < V1 + V2)  { src = p2; k = t - V1; }
            else                   { src = p3; k = t - V1 - V2; }
        }
        float x = src[3 * k], y = src[3 * k + 1], z = src[3 * k + 2];
        pk[i] = make_float4(x, y, z, x * x + y * y + z * z);
    }
}

/* Thread owns 2 A points (t, t+h); loops over B[j0,j1) at wave-uniform
   addresses with a 2-stage software pipeline.
   Tracks m = min_j (Bn - 2*A.B); final d = max(An + m, 0) (hoisted add,
   max commutes with min). atomicMin on float-as-uint valid: clamped >=0. */
__launch_bounds__(256)
__global__ void k_pair2(const float4* __restrict__ Ap, int NA,
                        const float4* __restrict__ Bp, int NB,
                        int chunk, unsigned int* __restrict__ outMin) {
    int h = (NA + 1) >> 1;
    int t = blockIdx.x * blockDim.x + threadIdx.x;
    if (t >= h) return;
    int j0 = blockIdx.y * chunk;
    if (j0 >= NB) return;
    int j1 = min(NB, j0 + chunk);
    int t2 = t + h;
    bool has2 = (t2 < NA);
    float4 a0 = Ap[t];
    float4 a1 = has2 ? Ap[t2] : a0;
    float p0x = -2.f * a0.x, p0y = -2.f * a0.y, p0z = -2.f * a0.z;
    float p1x = -2.f * a1.x, p1y = -2.f * a1.y, p1z = -2.f * a1.z;
    float inf = __builtin_inff();
    float m00 = inf, m01 = inf, m02 = inf, m03 = inf;
    float m10 = inf, m11 = inf, m12 = inf, m13 = inf;
#define P2(bb, k) { \
    float d0 = fmaf(p0x, bb.x, bb.w); d0 = fmaf(p0y, bb.y, d0); d0 = fmaf(p0z, bb.z, d0); \
    float d1 = fmaf(p1x, bb.x, bb.w); d1 = fmaf(p1y, bb.y, d1); d1 = fmaf(p1z, bb.z, d1); \
    m0##k = fminf(m0##k, d0); m1##k = fminf(m1##k, d1); }
    int j = j0;
    float4 b0, b1, b2, b3;
    bool have = (j + 4 <= j1);
    if (have) { b0 = Bp[j]; b1 = Bp[j + 1]; b2 = Bp[j + 2]; b3 = Bp[j + 3]; }
    for (; j + 8 <= j1; j += 4) {
        float4 n0 = Bp[j + 4], n1 = Bp[j + 5], n2 = Bp[j + 6], n3 = Bp[j + 7];
        P2(b0, 0) P2(b1, 1) P2(b2, 2) P2(b3, 3)
        b0 = n0; b1 = n1; b2 = n2; b3 = n3;
    }
    if (have) { P2(b0, 0) P2(b1, 1) P2(b2, 2) P2(b3, 3) j += 4; }
    for (; j < j1; ++j) { float4 b = Bp[j]; P2(b, 0) }
#undef P2
    float m0 = fminf(fminf(m00, m01), fminf(m02, m03));
    float m1 = fminf(fminf(m10, m11), fminf(m12, m13));
    float r0 = fmaxf(a0.w + m0, 0.0f);
    atomicMin(outMin + t, __float_as_uint(r0));
    if (has2) {
        float r1 = fmaxf(a1.w + m1, 0.0f);
        atomicMin(outMin + t2, __float_as_uint(r1));
    }
}

__global__ void k_reduce_chamfer(const unsigned int* __restrict__ d1,
                                 const unsigned int* __restrict__ d2,
                                 double* __restrict__ acc) {
    __shared__ double sm[8];
    double s = 0.0;
    int total  = ND1 + NPRED;
    int stride = gridDim.x * blockDim.x;
    for (int i = blockIdx.x * blockDim.x + threadIdx.x; i < total; i += stride) {
        double v, w;
        if (i < ND1) { v = (double)__uint_as_float(d1[i]); w = 1.0 / NG; }
        else {
            int t = i - ND1;
            v = (double)__uint_as_float(d2[t]);
            w = (t < V1) ? (1.0 / V1) : ((t < V1 + V2) ? (1.0 / V2) : (1.0 / V3));
        }
        s += v * w;
    }
    s = block_reduce_add(s, sm);
    if (threadIdx.x == 0) atomicAdd(acc + 0, s);
}

__global__ void k_edge(const float* __restrict__ p1, const float* __restrict__ p2,
                       const float* __restrict__ p3,
                       const int* __restrict__ e1, const int* __restrict__ e2,
                       const int* __restrict__ e3, double* __restrict__ acc) {
    __shared__ double sm[8];
    double s = 0.0;
    int total  = E1 + E2 + E3;
    int stride = gridDim.x * blockDim.x;
    for (int i = blockIdx.x * blockDim.x + threadIdx.x; i < total; i += stride) {
        const float* p; const int* e; int k; double w;
        if (i < E1)            { p = p1; e = e1; k = i;            w = 1.0 / E1; }
        else if (i < E1 + E2)  { p = p2; e = e2; k = i - E1;       w = 1.0 / E2; }
        else                   { p = p3; e = e3; k = i - E1 - E2;  w = 1.0 / E3; }
        int u = e[2 * k], v = e[2 * k + 1];
        float dx = p[3 * u]     - p[3 * v];
        float dy = p[3 * u + 1] - p[3 * v + 1];
        float dz = p[3 * u + 2] - p[3 * v + 2];
        s += w * (double)(dx * dx + dy * dy + dz * dz);
    }
    s = block_reduce_add(s, sm);
    if (threadIdx.x == 0) atomicAdd(acc + 1, s);
}

__global__ void k_lap(const float* __restrict__ f1, const float* __restrict__ f2,
                      const float* __restrict__ f3,
                      const float* __restrict__ p1, const float* __restrict__ p2,
                      const float* __restrict__ p3,
                      const int* __restrict__ l1, const int* __restrict__ l2,
                      const int* __restrict__ l3, double* __restrict__ acc) {
    __shared__ double sm[8];
    double s = 0.0;
    int stride = gridDim.x * blockDim.x;
    for (int i = blockIdx.x * blockDim.x + threadIdx.x; i < NPRED; i += stride) {
        const float* f; const float* p; const int* l; int k; double w;
        if (i < V1)            { f = f1; p = p1; l = l1; k = i;            w = 0.2 / V1; }
        else if (i < V1 + V2)  { f = f2; p = p2; l = l2; k = i - V1;       w = 1.0 / V2; }
        else                   { f = f3; p = p3; l = l3; k = i - V1 - V2;  w = 1.0 / V3; }
        const int* row = l + 10 * k;
        float sfx = 0.f, sfy = 0.f, sfz = 0.f, spx = 0.f, spy = 0.f, spz = 0.f;
#pragma unroll
        for (int q = 0; q < 8; ++q) {
            int n = row[q];
            if (n >= 0) {
                sfx += f[3 * n]; sfy += f[3 * n + 1]; sfz += f[3 * n + 2];
                spx += p[3 * n]; spy += p[3 * n + 1]; spz += p[3 * n + 2];
            }
        }
        float inv = 1.0f / (float)row[9];
        float dx = (f[3 * k]     - p[3 * k])     - (sfx - spx) * inv;
        float dy = (f[3 * k + 1] - p[3 * k + 1]) - (sfy - spy) * inv;
        float dz = (f[3 * k + 2] - p[3 * k + 2]) - (sfz - spz) * inv;
        s += w * (double)(dx * dx + dy * dy + dz * dz);
    }
    s = block_reduce_add(s, sm);
    if (threadIdx.x == 0) atomicAdd(acc + 2, s);
}

__global__ void k_final(const double* __restrict__ acc, float* __restrict__ out) {
    if (threadIdx.x == 0 && blockIdx.x == 0) {
        double ch = acc[0], ed = acc[1], lp = acc[2];
        out[0] = (float)(100.0 * ch + 0.1 * ed + 0.3 * lp);
        out[1] = (float)ch;
        out[2] = (float)ed;
        out[3] = (float)lp;
    }
}

static inline void launch_pair(const float4* A, int NA, const float4* B, int NB,
                               unsigned int* out, hipStream_t s) {
    int h  = (NA + 1) >> 1;
    int xb = (h + 255) / 256;
    int ny = (2048 + xb - 1) / xb;          /* target ~2048 blocks (8/CU)  */
    int maxNy = (NB + 31) / 32;             /* keep inner loop >= 32 iters */
    if (ny > maxNy) ny = maxNy;
    if (ny < 1) ny = 1;
    int chunk = (NB + ny - 1) / ny;
    dim3 g(xb, ny);
    k_pair2<<<g, 256, 0, s>>>(A, NA, B, NB, chunk, out);
}

extern "C" void kernel_launch(void* const* d_in, const int* in_sizes, int n_in,
                              void* d_out, int out_size, void* d_ws, size_t ws_size,
                              hipStream_t stream) {
    const float *pp[3], *pf[3], *gt;
    const int *ed[3], *li[3];
    if (in_sizes[1] == 3 * V1) {
        /* setup_inputs() dict order: (pts,feats,edges,lap)*3, gt */
        pp[0] = (const float*)d_in[0];  pf[0] = (const float*)d_in[1];
        ed[0] = (const int*)d_in[2];    li[0] = (const int*)d_in[3];
        pp[1] = (const float*)d_in[4];  pf[1] = (const float*)d_in[5];
        ed[1] = (const int*)d_in[6];    li[1] = (const int*)d_in[7];
        pp[2] = (const float*)d_in[8];  pf[2] = (const float*)d_in[9];
        ed[2] = (const int*)d_in[10];   li[2] = (const int*)d_in[11];
        gt = (const float*)d_in[12];
    } else {
        /* reference signature order */
        pp[0] = (const float*)d_in[0];  pp[1] = (const float*)d_in[1];  pp[2] = (const float*)d_in[2];
        pf[0] = (const float*)d_in[3];  pf[1] = (const float*)d_in[4];  pf[2] = (const float*)d_in[5];
        gt    = (const float*)d_in[6];
        ed[0] = (const int*)d_in[7];    ed[1] = (const int*)d_in[8];    ed[2] = (const int*)d_in[9];
        li[0] = (const int*)d_in[10];   li[1] = (const int*)d_in[11];   li[2] = (const int*)d_in[12];
    }

    char* ws = (char*)d_ws;
    double*       acc = (double*)ws;                       /* 8 doubles (64 B)   */
    float4*       pk  = (float4*)(ws + 64);                /* NPK float4         */
    unsigned int* d1  = (unsigned int*)(ws + 64 + (size_t)NPK * 16); /* 3*NG     */
    unsigned int* d2  = d1 + ND1;                          /* NPRED              */

    k_init<<<160, 256, 0, stream>>>(d1, acc);
    k_pack<<<242, 256, 0, stream>>>(gt, pp[0], pp[1], pp[2], pk);

    const float4* gtp = pk;
    const float4* pkp[3] = { pk + NG, pk + NG + V1, pk + NG + V1 + V2 };
    const int Vn[3] = { V1, V2, V3 };

    /* d1[i][t] = min over pred_i of dist(gt_t, .) */
    for (int i = 0; i < 3; ++i)
        launch_pair(gtp, NG, pkp[i], Vn[i], d1 + i * NG, stream);
    /* d2[j] = min over gt of dist(pred_j, .) */
    unsigned int* d2off[3] = { d2, d2 + V1, d2 + V1 + V2 };
    for (int i = 0; i < 3; ++i)
        launch_pair(pkp[i], Vn[i], gtp, NG, d2off[i], stream);

    k_reduce_chamfer<<<152, 256, 0, stream>>>(d1, d2, acc);
    k_edge<<<256, 256, 0, stream>>>(pp[0], pp[1], pp[2], ed[0], ed[1], ed[2], acc);
    k_lap<<<128, 256, 0, stream>>>(pf[0], pf[1], pf[2], pp[0], pp[1], pp[2],
                                   li[0], li[1], li[2], acc);
    k_final<<<1, 64, 0, stream>>>(acc, (float*)d_out);
}

// Round 4
// 199.894 us; speedup vs baseline: 2.0623x; 1.2159x over previous
//
#include <hip/hip_runtime.h>

#define NG 8000
#define V1 2562
#define V2 10242
#define V3 40962
#define E1 7680
#define E2 30720
#define E3 122880
#define NPRED (V1 + V2 + V3)   /* 53766 */
#define NPK   (NG + NPRED)     /* 61766 */
#define ND1   (3 * NG)         /* 24000 */
#define TILE  1024             /* B-chunk staged in LDS: 16 KB */

__device__ __forceinline__ double block_reduce_add(double v, double* sm) {
    int lane = threadIdx.x & 63;
    int wid  = threadIdx.x >> 6;
    for (int off = 32; off > 0; off >>= 1) v += __shfl_down(v, off, 64);
    if (lane == 0) sm[wid] = v;
    __syncthreads();
    double r = 0.0;
    if (wid == 0) {
        int nw = blockDim.x >> 6;
        r = (lane < nw) ? sm[lane] : 0.0;
        for (int off = 32; off > 0; off >>= 1) r += __shfl_down(r, off, 64);
    }
    return r;  /* valid on thread 0 */
}

__global__ void k_init(unsigned int* __restrict__ mins, double* __restrict__ acc) {
    int i = blockIdx.x * blockDim.x + threadIdx.x;
    if (i < 8) acc[i] = 0.0;
    int stride = gridDim.x * blockDim.x;
    for (int k = i; k < ND1 + NPRED; k += stride) mins[k] = 0x7f800000u; /* +inf */
}

__global__ void k_pack(const float* __restrict__ gt,
                       const float* __restrict__ p1, const float* __restrict__ p2,
                       const float* __restrict__ p3, float4* __restrict__ pk) {
    int stride = gridDim.x * blockDim.x;
    for (int i = blockIdx.x * blockDim.x + threadIdx.x; i < NPK; i += stride) {
        const float* src; int k;
        if (i < NG) { src = gt; k = i; }
        else {
            int t = i - NG;
            if (t < V1)            { src = p1; k = t; }
            else if (t < V1 + V2)  { src = p2; k = t - V1; }
            else                   { src = p3; k = t - V1 - V2; }
        }
        float x = src[3 * k], y = src[3 * k + 1], z = src[3 * k + 2];
        pk[i] = make_float4(x, y, z, x * x + y * y + z * z);
    }
}

/* Thread owns 4 A points (t, t+h, t+2h, t+3h). Block stages its B-chunk
   (<= TILE float4) into LDS once; inner loop reads LDS at wave-uniform
   addresses (broadcast, conflict-free, imm offsets). Tracks
   m = min_j (Bn - 2*A.B); final d = max(An + m, 0) — the An+ add is
   hoisted (min is translation-invariant) and max commutes with min.
   atomicMin on float-as-uint is order-correct since values are >= 0. */
__launch_bounds__(256)
__global__ void k_pair4(const float4* __restrict__ Ap, int NA,
                        const float4* __restrict__ Bp, int NB,
                        int chunk, unsigned int* __restrict__ outMin) {
    __shared__ float4 sb[TILE];
    int h  = (NA + 3) >> 2;
    int t  = blockIdx.x * blockDim.x + threadIdx.x;
    int j0 = blockIdx.y * chunk;
    int j1 = min(NB, j0 + chunk);
    int cnt = j1 - j0;
    for (int k = threadIdx.x; k < cnt; k += 256) sb[k] = Bp[j0 + k];
    __syncthreads();
    if (t >= h) return;

    int t1 = t + h, t2 = t + 2 * h, t3 = t + 3 * h;
    float4 a0 = Ap[t];
    float4 a1 = Ap[min(t1, NA - 1)];
    float4 a2 = Ap[min(t2, NA - 1)];
    float4 a3 = Ap[min(t3, NA - 1)];
    float n0x = -2.f * a0.x, n0y = -2.f * a0.y, n0z = -2.f * a0.z;
    float n1x = -2.f * a1.x, n1y = -2.f * a1.y, n1z = -2.f * a1.z;
    float n2x = -2.f * a2.x, n2y = -2.f * a2.y, n2z = -2.f * a2.z;
    float n3x = -2.f * a3.x, n3y = -2.f * a3.y, n3z = -2.f * a3.z;
    float inf = __builtin_inff();
    float m0 = inf, m1 = inf, m2 = inf, m3 = inf;

#define DOT(nx, ny, nz, bb) fmaf(nz, bb.z, fmaf(ny, bb.y, fmaf(nx, bb.x, bb.w)))
    int k = 0;
    for (; k + 8 <= cnt; k += 8) {
#pragma unroll
        for (int u = 0; u < 8; u += 2) {
            float4 b0 = sb[k + u];
            float4 b1 = sb[k + u + 1];
            float d00 = DOT(n0x, n0y, n0z, b0), d01 = DOT(n0x, n0y, n0z, b1);
            float d10 = DOT(n1x, n1y, n1z, b0), d11 = DOT(n1x, n1y, n1z, b1);
            float d20 = DOT(n2x, n2y, n2z, b0), d21 = DOT(n2x, n2y, n2z, b1);
            float d30 = DOT(n3x, n3y, n3z, b0), d31 = DOT(n3x, n3y, n3z, b1);
            m0 = fminf(fminf(m0, d00), d01);   /* -> v_min3_f32 */
            m1 = fminf(fminf(m1, d10), d11);
            m2 = fminf(fminf(m2, d20), d21);
            m3 = fminf(fminf(m3, d30), d31);
        }
    }
    for (; k < cnt; ++k) {
        float4 b = sb[k];
        m0 = fminf(m0, DOT(n0x, n0y, n0z, b));
        m1 = fminf(m1, DOT(n1x, n1y, n1z, b));
        m2 = fminf(m2, DOT(n2x, n2y, n2z, b));
        m3 = fminf(m3, DOT(n3x, n3y, n3z, b));
    }
#undef DOT
    atomicMin(outMin + t, __float_as_uint(fmaxf(a0.w + m0, 0.f)));
    if (t1 < NA) atomicMin(outMin + t1, __float_as_uint(fmaxf(a1.w + m1, 0.f)));
    if (t2 < NA) atomicMin(outMin + t2, __float_as_uint(fmaxf(a2.w + m2, 0.f)));
    if (t3 < NA) atomicMin(outMin + t3, __float_as_uint(fmaxf(a3.w + m3, 0.f)));
}

/* chamfer-reduce + edge + laplace fused: three independent grid-stride
   segments, three double partial sums, one atomicAdd each per block. */
#define R0 (ND1 + NPRED)
#define R1 (E1 + E2 + E3)
#define R2 NPRED
__global__ void k_post(const unsigned int* __restrict__ d1,
                       const unsigned int* __restrict__ d2,
                       const float* __restrict__ p1, const float* __restrict__ p2,
                       const float* __restrict__ p3,
                       const int* __restrict__ e1, const int* __restrict__ e2,
                       const int* __restrict__ e3,
                       const float* __restrict__ f1, const float* __restrict__ f2,
                       const float* __restrict__ f3,
                       const int* __restrict__ l1, const int* __restrict__ l2,
                       const int* __restrict__ l3,
                       double* __restrict__ acc) {
    __shared__ double sm[8];
    double s0 = 0.0, s1 = 0.0, s2 = 0.0;
    int stride = gridDim.x * blockDim.x;
    int gid = blockIdx.x * blockDim.x + threadIdx.x;
    for (int i = gid; i < R0 + R1 + R2; i += stride) {
        if (i < R0) {
            double v, w;
            if (i < ND1) { v = (double)__uint_as_float(d1[i]); w = 1.0 / NG; }
            else {
                int t = i - ND1;
                v = (double)__uint_as_float(d2[t]);
                w = (t < V1) ? (1.0 / V1) : ((t < V1 + V2) ? (1.0 / V2) : (1.0 / V3));
            }
            s0 += v * w;
        } else if (i < R0 + R1) {
            int q = i - R0;
            const float* p; const int* e; int k; double w;
            if (q < E1)            { p = p1; e = e1; k = q;            w = 1.0 / E1; }
            else if (q < E1 + E2)  { p = p2; e = e2; k = q - E1;       w = 1.0 / E2; }
            else                   { p = p3; e = e3; k = q - E1 - E2;  w = 1.0 / E3; }
            int u = e[2 * k], v = e[2 * k + 1];
            float dx = p[3 * u]     - p[3 * v];
            float dy = p[3 * u + 1] - p[3 * v + 1];
            float dz = p[3 * u + 2] - p[3 * v + 2];
            s1 += w * (double)(dx * dx + dy * dy + dz * dz);
        } else {
            int q = i - R0 - R1;
            const float* f; const float* p; const int* l; int k; double w;
            if (q < V1)            { f = f1; p = p1; l = l1; k = q;            w = 0.2 / V1; }
            else if (q < V1 + V2)  { f = f2; p = p2; l = l2; k = q - V1;       w = 1.0 / V2; }
            else                   { f = f3; p = p3; l = l3; k = q - V1 - V2;  w = 1.0 / V3; }
            const int* row = l + 10 * k;
            float sfx = 0.f, sfy = 0.f, sfz = 0.f, spx = 0.f, spy = 0.f, spz = 0.f;
#pragma unroll
            for (int r = 0; r < 8; ++r) {
                int n = row[r];
                if (n >= 0) {
                    sfx += f[3 * n]; sfy += f[3 * n + 1]; sfz += f[3 * n + 2];
                    spx += p[3 * n]; spy += p[3 * n + 1]; spz += p[3 * n + 2];
                }
            }
            float inv = 1.0f / (float)row[9];
            float dx = (f[3 * k]     - p[3 * k])     - (sfx - spx) * inv;
            float dy = (f[3 * k + 1] - p[3 * k + 1]) - (sfy - spy) * inv;
            float dz = (f[3 * k + 2] - p[3 * k + 2]) - (sfz - spz) * inv;
            s2 += w * (double)(dx * dx + dy * dy + dz * dz);
        }
    }
    double r0 = block_reduce_add(s0, sm); __syncthreads();
    double r1 = block_reduce_add(s1, sm); __syncthreads();
    double r2 = block_reduce_add(s2, sm);
    if (threadIdx.x == 0) {
        atomicAdd(acc + 0, r0);
        atomicAdd(acc + 1, r1);
        atomicAdd(acc + 2, r2);
    }
}

__global__ void k_final(const double* __restrict__ acc, float* __restrict__ out) {
    if (threadIdx.x == 0 && blockIdx.x == 0) {
        double ch = acc[0], ed = acc[1], lp = acc[2];
        out[0] = (float)(100.0 * ch + 0.1 * ed + 0.3 * lp);
        out[1] = (float)ch;
        out[2] = (float)ed;
        out[3] = (float)lp;
    }
}

static inline void launch_pair(const float4* A, int NA, const float4* B, int NB,
                               unsigned int* out, hipStream_t s) {
    int h   = (NA + 3) >> 2;
    int xb  = (h + 255) / 256;
    int ny  = (2048 + xb - 1) / xb;          /* target ~2048 blocks (8/CU)   */
    int maxNy = NB / 32;                     /* keep inner loop >= ~32 iters */
    if (maxNy < 1) maxNy = 1;
    if (ny > maxNy) ny = maxNy;
    int nyT = (NB + TILE - 1) / TILE;        /* chunk must fit LDS tile      */
    if (ny < nyT) ny = nyT;
    int chunk = (NB + ny - 1) / ny;
    dim3 g(xb, ny);
    k_pair4<<<g, 256, 0, s>>>(A, NA, B, NB, chunk, out);
}

extern "C" void kernel_launch(void* const* d_in, const int* in_sizes, int n_in,
                              void* d_out, int out_size, void* d_ws, size_t ws_size,
                              hipStream_t stream) {
    const float *pp[3], *pf[3], *gt;
    const int *ed[3], *li[3];
    if (in_sizes[1] == 3 * V1) {
        /* setup_inputs() dict order: (pts,feats,edges,lap)*3, gt */
        pp[0] = (const float*)d_in[0];  pf[0] = (const float*)d_in[1];
        ed[0] = (const int*)d_in[2];    li[0] = (const int*)d_in[3];
        pp[1] = (const float*)d_in[4];  pf[1] = (const float*)d_in[5];
        ed[1] = (const int*)d_in[6];    li[1] = (const int*)d_in[7];
        pp[2] = (const float*)d_in[8];  pf[2] = (const float*)d_in[9];
        ed[2] = (const int*)d_in[10];   li[2] = (const int*)d_in[11];
        gt = (const float*)d_in[12];
    } else {
        /* reference signature order */
        pp[0] = (const float*)d_in[0];  pp[1] = (const float*)d_in[1];  pp[2] = (const float*)d_in[2];
        pf[0] = (const float*)d_in[3];  pf[1] = (const float*)d_in[4];  pf[2] = (const float*)d_in[5];
        gt    = (const float*)d_in[6];
        ed[0] = (const int*)d_in[7];    ed[1] = (const int*)d_in[8];    ed[2] = (const int*)d_in[9];
        li[0] = (const int*)d_in[10];   li[1] = (const int*)d_in[11];   li[2] = (const int*)d_in[12];
    }

    char* ws = (char*)d_ws;
    double*       acc = (double*)ws;                       /* 8 doubles (64 B)   */
    float4*       pk  = (float4*)(ws + 64);                /* NPK float4         */
    unsigned int* d1  = (unsigned int*)(ws + 64 + (size_t)NPK * 16); /* 3*NG     */
    unsigned int* d2  = d1 + ND1;                          /* NPRED              */

    k_init<<<160, 256, 0, stream>>>(d1, acc);
    k_pack<<<242, 256, 0, stream>>>(gt, pp[0], pp[1], pp[2], pk);

    const float4* gtp = pk;
    const float4* pkp[3] = { pk + NG, pk + NG + V1, pk + NG + V1 + V2 };
    const int Vn[3] = { V1, V2, V3 };

    /* d1[i][t] = min over pred_i of dist(gt_t, .) */
    for (int i = 0; i < 3; ++i)
        launch_pair(gtp, NG, pkp[i], Vn[i], d1 + i * NG, stream);
    /* d2[j] = min over gt of dist(pred_j, .) */
    unsigned int* d2off[3] = { d2, d2 + V1, d2 + V1 + V2 };
    for (int i = 0; i < 3; ++i)
        launch_pair(pkp[i], Vn[i], gtp, NG, d2off[i], stream);

    k_post<<<256, 256, 0, stream>>>(d1, d2, pp[0], pp[1], pp[2],
                                    ed[0], ed[1], ed[2],
                                    pf[0], pf[1], pf[2],
                                    li[0], li[1], li[2], acc);
    k_final<<<1, 64, 0, stream>>>(acc, (float*)d_out);
}